// Round 1
// baseline (154.771 us; speedup 1.0000x reference)
//
#include <hip/hip_runtime.h>
#include <math.h>

#define T 4096
#define C 256
#define BATCH 2
#define NH 4
#define G 32
#define CPG 8
#define EPS 1e-5f
#define LOG2E 1.4426950408889634f
// Reference applies scale=ch^-0.25 to q AND k -> logit = (q.k)/8. Fold /8 and
// log2e (exp2-domain softmax) into Q once.
#define QSCALE (0.125f * LOG2E)
#define KSPLIT 4
#define KRANGE (T / KSPLIT)
#define BH (BATCH * NH)

typedef __attribute__((ext_vector_type(8))) short bfv8;
typedef __attribute__((ext_vector_type(4))) short bfv4;
typedef __attribute__((ext_vector_type(4))) float f32x4;

static __device__ __forceinline__ short f2bf(float f) {
    union { float f; unsigned u; } v; v.f = f;
    return (short)((v.u + 0x7FFFu + ((v.u >> 16) & 1u)) >> 16);
}
static __device__ __forceinline__ float bf2f(short s) {
    union { float f; unsigned u; } v; v.u = ((unsigned)(unsigned short)s) << 16;
    return v.f;
}

#if __has_builtin(__builtin_amdgcn_exp2f)
#define EXP2(x) __builtin_amdgcn_exp2f(x)
#else
#define EXP2(x) exp2f(x)
#endif

#define AS1 __attribute__((address_space(1)))
#define AS3 __attribute__((address_space(3)))
static __device__ __forceinline__ void gll16(const void* g, void* l) {
    __builtin_amdgcn_global_load_lds((const AS1 void*)g, (AS3 void*)l, 16, 0, 0);
}

// ---------------------------------------------------------------------------
// Weight prep: fp32 -> bf16 for w_qkv [768,256] and w_proj [256,256]
// ---------------------------------------------------------------------------
__global__ __launch_bounds__(256) void prep_w(const float* __restrict__ wq,
                                              const float* __restrict__ wp,
                                              short* __restrict__ wqb,
                                              short* __restrict__ wpb) {
    int i = blockIdx.x * 256 + threadIdx.x;   // float4 index
    const int NQ = 768 * 256 / 4;
    float4 v; short* dst;
    if (i < NQ) { v = ((const float4*)wq)[i]; dst = wqb + i * 4; }
    else        { int j = i - NQ; v = ((const float4*)wp)[j]; dst = wpb + j * 4; }
    bfv4 o = { f2bf(v.x), f2bf(v.y), f2bf(v.z), f2bf(v.w) };
    *(bfv4*)dst = o;
}

// ---------------------------------------------------------------------------
// GroupNorm stats pass: grid (B*G, 4 t-splits), 256 thr.
// ---------------------------------------------------------------------------
__global__ __launch_bounds__(256) void gn_stats(const float* __restrict__ x,
                                                float* __restrict__ gnp) {
    const int blk = blockIdx.x;            // b*G+g
    const int ts  = blockIdx.y;            // 0..3
    const int b = blk / G, g = blk % G;
    const float* xp = x + ((size_t)b * C + g * CPG) * T + ts * 1024;

    const int tid = threadIdx.x;
    float s = 0.f, ss = 0.f;
    #pragma unroll
    for (int u = 0; u < CPG; u++) {
        float4 v = ((const float4*)(xp + (size_t)u * T))[tid];
        s  += v.x + v.y + v.z + v.w;
        ss += v.x*v.x + v.y*v.y + v.z*v.z + v.w*v.w;
    }
    __shared__ float rs[256], rss[256];
    rs[tid] = s; rss[tid] = ss;
    __syncthreads();
    for (int off = 128; off > 0; off >>= 1) {
        if (tid < off) { rs[tid] += rs[tid+off]; rss[tid] += rss[tid+off]; }
        __syncthreads();
    }
    if (tid == 0) {
        gnp[(blk * 4 + ts) * 2 + 0] = rs[0];
        gnp[(blk * 4 + ts) * 2 + 1] = rss[0];
    }
}

// ---------------------------------------------------------------------------
// GroupNorm normalize pass: grid (B*G, 4 t-splits), 256 thr -> bf16 xnT[b][t][c]
// ---------------------------------------------------------------------------
__global__ __launch_bounds__(256) void gn_norm(const float* __restrict__ x,
                                               const float* __restrict__ scale,
                                               const float* __restrict__ bias,
                                               const float* __restrict__ gnp,
                                               short* __restrict__ xnT) {
    const int blk = blockIdx.x;            // b*G+g
    const int ts  = blockIdx.y;            // 0..3
    const int b = blk / G, g = blk % G;
    const int c0 = g * CPG;
    const float* xp = x + ((size_t)b * C + c0) * T;

    float s = 0.f, ss = 0.f;
    #pragma unroll
    for (int i = 0; i < 4; i++) {
        s  += gnp[(blk * 4 + i) * 2 + 0];
        ss += gnp[(blk * 4 + i) * 2 + 1];
    }
    const float inv_n = 1.0f / (CPG * T);
    const float mu  = s * inv_n;
    const float var = ss * inv_n - mu * mu;
    const float rstd = rsqrtf(var + EPS);

    float sc[CPG], bi[CPG];
    #pragma unroll
    for (int u = 0; u < CPG; u++) {
        sc[u] = scale[c0+u] * rstd;
        bi[u] = bias[c0+u] - mu * sc[u];
    }

    const int t = ts * 1024 + threadIdx.x * 4;
    float vv[CPG][4];
    #pragma unroll
    for (int u = 0; u < CPG; u++) {
        float4 v = *(const float4*)&xp[(size_t)u * T + t];
        vv[u][0] = v.x * sc[u] + bi[u];
        vv[u][1] = v.y * sc[u] + bi[u];
        vv[u][2] = v.z * sc[u] + bi[u];
        vv[u][3] = v.w * sc[u] + bi[u];
    }
    #pragma unroll
    for (int j = 0; j < 4; j++) {
        bfv8 w = { f2bf(vv[0][j]), f2bf(vv[1][j]), f2bf(vv[2][j]), f2bf(vv[3][j]),
                   f2bf(vv[4][j]), f2bf(vv[5][j]), f2bf(vv[6][j]), f2bf(vv[7][j]) };
        *(bfv8*)&xnT[((size_t)b * T + t + j) * C + c0] = w;
    }
}

// ---------------------------------------------------------------------------
// qkv GEMM (bf16 MFMA, BK=64 — R9/R11/R13): grid (T/64, 12, BATCH), 256 thr.
// ---------------------------------------------------------------------------
__global__ __launch_bounds__(256) void gemm_qkv(
    const short* __restrict__ wq,    // [768][256] bf16
    const float* __restrict__ bq,    // [768]
    const short* __restrict__ xnT,   // [B][T][C] bf16
    short* __restrict__ qb, short* __restrict__ kb, short* __restrict__ vb)
{
    const int b  = blockIdx.z;
    const int t0 = blockIdx.x * 64;
    const int ot = blockIdx.y;
    const int h = ot / 3, part = ot % 3;
    const int o0 = ot * 64;

    __shared__ short sm[8192];       // A 8x512 + B 8x512 shorts (16 KiB)
    short* Ab = sm;
    short* Bb = sm + 4096;

    const int tid = threadIdx.x, lane = tid & 63, wave = tid >> 6;
    const int col = lane & 15, quad = lane >> 4;
    const short* xb = xnT + (size_t)b * T * C;

    f32x4 acc[4];
    #pragma unroll
    for (int g = 0; g < 4; g++) { acc[g][0]=0.f; acc[g][1]=0.f; acc[g][2]=0.f; acc[g][3]=0.f; }

    for (int k0 = 0; k0 < C; k0 += 64) {
        __syncthreads();
        #pragma unroll
        for (int hh = 0; hh < 2; hh++) {
            gll16(wq + (size_t)(o0 + 16*wave + col) * C + k0 + hh*32 + quad*8,
                  Ab + (hh*4 + wave) * 512);
            gll16(xb + (size_t)(t0 + 16*wave + col) * C + k0 + hh*32 + quad*8,
                  Bb + (hh*4 + wave) * 512);
        }
        __syncthreads();
        #pragma unroll
        for (int hh = 0; hh < 2; hh++) {
            bfv8 af = *(const bfv8*)(Ab + (hh*4 + wave) * 512 + lane*8);
            #pragma unroll
            for (int g = 0; g < 4; g++) {
                bfv8 bf = *(const bfv8*)(Bb + (hh*4 + g) * 512 + lane*8);
                acc[g] = __builtin_amdgcn_mfma_f32_16x16x32_bf16(af, bf, acc[g], 0, 0, 0);
            }
        }
    }

    const int olocal = 16*wave + quad*4;
    float bias_r[4];
    #pragma unroll
    for (int r = 0; r < 4; r++) bias_r[r] = bq[o0 + olocal + r];
    const size_t hd = (size_t)(b * NH + h);

    if (part < 2) {
        short* dst = (part == 0 ? qb : kb) + hd * T * 64;
        const float sc = (part == 0) ? QSCALE : 1.0f;
        #pragma unroll
        for (int g = 0; g < 4; g++) {
            int t = t0 + 16*g + col;
            bfv4 w = { f2bf((acc[g][0] + bias_r[0]) * sc),
                       f2bf((acc[g][1] + bias_r[1]) * sc),
                       f2bf((acc[g][2] + bias_r[2]) * sc),
                       f2bf((acc[g][3] + bias_r[3]) * sc) };
            *(bfv4*)&dst[(size_t)t * 64 + olocal] = w;
        }
    } else {
        short* dst = vb + hd * 64 * T;
        #pragma unroll
        for (int g = 0; g < 4; g++)
            #pragma unroll
            for (int r = 0; r < 4; r++)
                dst[(size_t)(olocal + r) * T + t0 + 16*g + col] =
                    f2bf(acc[g][r] + bias_r[r]);
    }
}

// ---------------------------------------------------------------------------
// Flash attention v9: v8's 8-wave dual-sub S^T dbuf body, with the PV step
// upgraded from 32x mfma_16x16x16 (K=16) to 16x mfma_16x16x32 (K=32) per
// iter. The K=32 B-operand (P^T) is built in-register via v_cvt_pk_bf16_f32
// (2 f32->bf16/op) + v_permlane32_swap_b32 (dst.hi <-> src.lo), which yields
// the frag under key permutation pi = {0-3,8-11 | 4-7,12-15 | 16-19,24-27 |
// 20-23,28-31}; the V A-operand applies the SAME pi via its LDS addresses
// (2x ds_read_b64 per frag — same LDS op count as v8). Replaces ~160 VALU
// ops/iter of f2bf+pack with 16 cvt_pk + 8 permlane, and halves PV MFMA
// instruction count at ~1.65x the per-instruction FLOP rate.
// grid (T/256, BH, KSPLIT) = 512 blocks = 2/CU even.
// ---------------------------------------------------------------------------
__global__ __launch_bounds__(512) void attn_kernel(
    const short* __restrict__ qb,    // [BH][T][64] (pre-scaled by QSCALE)
    const short* __restrict__ kb,    // [BH][T][64]
    const short* __restrict__ vb,    // [BH][64][T]
    short* __restrict__ opart,       // [KSPLIT][BH][T][64] unnormalized O, bf16
    float* __restrict__ lp)          // [KSPLIT][BH][T]
{
    __shared__ short smem[16384];    // 2 x (K 8KB + V 8KB) = 32 KiB
    const int bh = blockIdx.y;
    const int ks = blockIdx.z;
    const int t0 = blockIdx.x * 256;
    const int k0base = ks * KRANGE;
    const short* kbh = kb + (size_t)bh * T * 64;
    const short* vbh = vb + (size_t)bh * 64 * T;

    const int tid  = threadIdx.x;
    const int lane = tid & 63;
    const int wave = tid >> 6;       // 0..7
    const int col  = lane & 15;
    const int quad = lane >> 4;

    // Q fragments for both sub-tiles (B-operand for S^T)
    const short* qrowA = qb + (size_t)bh * T * 64 + (size_t)(t0 + wave*16 + col) * 64;
    const short* qrowB = qrowA + (size_t)128 * 64;
    bfv8 qfA0 = *(const bfv8*)(qrowA + quad*8);
    bfv8 qfA1 = *(const bfv8*)(qrowA + 32 + quad*8);
    bfv8 qfB0 = *(const bfv8*)(qrowB + quad*8);
    bfv8 qfB1 = *(const bfv8*)(qrowB + 32 + quad*8);

    f32x4 oaccA[4], oaccB[4];  // O^T C-layout: ch = 16g+quad*4+r, q = col
    #pragma unroll
    for (int g = 0; g < 4; g++) {
        oaccA[g][0]=0.f; oaccA[g][1]=0.f; oaccA[g][2]=0.f; oaccA[g][3]=0.f;
        oaccB[g][0]=0.f; oaccB[g][1]=0.f; oaccB[g][2]=0.f; oaccB[g][3]=0.f;
    }
    float lsumA = 0.f, lsumB = 0.f;

    // V A-frag base (shorts): pi-permuted key octet for this quad.
    //   first b64: keys 8*(quad>>1)... hmm, concretely: within a 32-key chunk
    //   quad q reads keys {8*(q>>1)*2 + (q&1)*4 + 0..3} and {+8..}:
    //   addr = col*8 + (q&1)*4 + (q>>1)*256, second read at +128 shorts.
    const int voff = col*8 + (quad & 1)*4 + (quad >> 1)*256;

    // 8-wave staging: wave w stages K slot w and V slot w (one gll16 each).
    // Slot s<4: K keys 16s+col ch quad*8 / V ch 16s+col keys quad*8;
    // slot s>=4: same rows, ch/keys 32+quad*8.  (kg = w&3, hi = w>>2)
    const int kg = wave & 3, hi = wave >> 2;
    #define STAGE_KV(buf, s0)                                                  \
        {                                                                      \
            short* base = smem + (buf) * 8192;                                 \
            gll16(kbh + (size_t)((s0) + 16*kg + col) * 64 + (quad + 4*hi)*8,   \
                  base + wave * 512);                                          \
            gll16(vbh + (size_t)(16*kg + col) * T + (s0) + (quad + 4*hi)*8,    \
                  base + 4096 + wave * 512);                                   \
        }

    STAGE_KV(0, k0base)

    for (int it = 0; it < KRANGE/64; it++) {
        __syncthreads();                        // staged tile visible
        if (it + 1 < KRANGE/64) STAGE_KV((it+1) & 1, k0base + (it+1)*64)

        const short* kvb = smem + (it & 1) * 8192;

        // S^T per group: K-frag read once, feeds both sub-tiles.
        // P packed to bf16 pairs: pw[chunk][X0,X1,Y0,Y1] pre-swap, where
        // chunk = g>>1, X = even g, Y = odd g.
        unsigned pwA[2][4], pwB[2][4];
        #pragma unroll
        for (int g = 0; g < 4; g++) {
            bfv8 kf0 = *(const bfv8*)(kvb + g*512 + lane*8);
            bfv8 kf1 = *(const bfv8*)(kvb + (4+g)*512 + lane*8);
            f32x4 a;
            a[0]=0.f; a[1]=0.f; a[2]=0.f; a[3]=0.f;
            a = __builtin_amdgcn_mfma_f32_16x16x32_bf16(kf0, qfA0, a, 0, 0, 0);
            a = __builtin_amdgcn_mfma_f32_16x16x32_bf16(kf1, qfA1, a, 0, 0, 0);
            {
                float p0 = EXP2(a[0]), p1 = EXP2(a[1]);
                float p2 = EXP2(a[2]), p3 = EXP2(a[3]);
                lsumA += (p0 + p1) + (p2 + p3);
                asm("v_cvt_pk_bf16_f32 %0, %1, %2"
                    : "=v"(pwA[g>>1][(g&1)*2+0]) : "v"(p0), "v"(p1));
                asm("v_cvt_pk_bf16_f32 %0, %1, %2"
                    : "=v"(pwA[g>>1][(g&1)*2+1]) : "v"(p2), "v"(p3));
            }
            a[0]=0.f; a[1]=0.f; a[2]=0.f; a[3]=0.f;
            a = __builtin_amdgcn_mfma_f32_16x16x32_bf16(kf0, qfB0, a, 0, 0, 0);
            a = __builtin_amdgcn_mfma_f32_16x16x32_bf16(kf1, qfB1, a, 0, 0, 0);
            {
                float p0 = EXP2(a[0]), p1 = EXP2(a[1]);
                float p2 = EXP2(a[2]), p3 = EXP2(a[3]);
                lsumB += (p0 + p1) + (p2 + p3);
                asm("v_cvt_pk_bf16_f32 %0, %1, %2"
                    : "=v"(pwB[g>>1][(g&1)*2+0]) : "v"(p0), "v"(p1));
                asm("v_cvt_pk_bf16_f32 %0, %1, %2"
                    : "=v"(pwB[g>>1][(g&1)*2+1]) : "v"(p2), "v"(p3));
            }
        }

        // Redistribute halves: after swap, X0' = [X0.lo32, Y0.lo32] (frag w0),
        // Y0' = [X0.hi32, Y0.hi32] (frag w2); same for X1/Y1 -> w1/w3.
        #pragma unroll
        for (int cc = 0; cc < 2; cc++) {
            asm("v_permlane32_swap_b32 %0, %1" : "+v"(pwA[cc][0]), "+v"(pwA[cc][2]));
            asm("v_permlane32_swap_b32 %0, %1" : "+v"(pwA[cc][1]), "+v"(pwA[cc][3]));
            asm("v_permlane32_swap_b32 %0, %1" : "+v"(pwB[cc][0]), "+v"(pwB[cc][2]));
            asm("v_permlane32_swap_b32 %0, %1" : "+v"(pwB[cc][1]), "+v"(pwB[cc][3]));
        }

        // O^T += V P^T with K=32 MFMA: V A-frags read with the same key
        // permutation pi; each frag = 2x ds_read_b64, fed to both sub-tiles.
        const short* vbase = kvb + 4096 + voff;
        #pragma unroll
        for (int cc = 0; cc < 2; cc++) {
            union { unsigned u[4]; bfv8 v; } fa, fb;
            fa.u[0]=pwA[cc][0]; fa.u[1]=pwA[cc][1]; fa.u[2]=pwA[cc][2]; fa.u[3]=pwA[cc][3];
            fb.u[0]=pwB[cc][0]; fb.u[1]=pwB[cc][1]; fb.u[2]=pwB[cc][2]; fb.u[3]=pwB[cc][3];
            #pragma unroll
            for (int g = 0; g < 4; g++) {
                const short* vp = vbase + cc*2048 + g*512;
                bfv4 lo = *(const bfv4*)vp;
                bfv4 hi = *(const bfv4*)(vp + 128);
                bfv8 vf = { lo[0], lo[1], lo[2], lo[3],
                            hi[0], hi[1], hi[2], hi[3] };
                oaccA[g] = __builtin_amdgcn_mfma_f32_16x16x32_bf16(vf, fa.v, oaccA[g], 0, 0, 0);
                oaccB[g] = __builtin_amdgcn_mfma_f32_16x16x32_bf16(vf, fb.v, oaccB[g], 0, 0, 0);
            }
        }
    }

    // l: quads partition the 64 keys for query=col -> reduce across quads
    lsumA += __shfl_xor(lsumA, 16);
    lsumA += __shfl_xor(lsumA, 32);
    lsumB += __shfl_xor(lsumB, 16);
    lsumB += __shfl_xor(lsumB, 32);

    // epilogue: lane owns t-rows (wave*16 | 128+wave*16)+col, ch 16g+quad*4..+3
    const size_t rowbaseA = (size_t)(ks*BH + bh) * T + t0 + wave*16;
    const size_t rowbaseB = rowbaseA + 128;
    short* opbA = opart + (rowbaseA + col) * 64;
    short* opbB = opart + (rowbaseB + col) * 64;
    #pragma unroll
    for (int g = 0; g < 4; g++) {
        bfv4 wA = { f2bf(oaccA[g][0]), f2bf(oaccA[g][1]),
                    f2bf(oaccA[g][2]), f2bf(oaccA[g][3]) };
        *(bfv4*)(opbA + 16*g + quad*4) = wA;
        bfv4 wB = { f2bf(oaccB[g][0]), f2bf(oaccB[g][1]),
                    f2bf(oaccB[g][2]), f2bf(oaccB[g][3]) };
        *(bfv4*)(opbB + 16*g + quad*4) = wB;
    }
    if (lane < 16) {
        lp[rowbaseA + col] = lsumA;
        lp[rowbaseB + col] = lsumB;
    }
}

// ---------------------------------------------------------------------------
// proj GEMM (bf16 MFMA, BK=64) with fused combine (R9/R11/R13): B-operand
// built from opart (sum KSPLIT partials x per-head rl). + bias + fp32 resid.
// grid (T/64, 4, BATCH).
// ---------------------------------------------------------------------------
__global__ __launch_bounds__(256) void gemm_proj(
    const short* __restrict__ wp,    // [256][256] bf16
    const float* __restrict__ bp,    // [256]
    const short* __restrict__ opart, // [KSPLIT][BH][T][64] bf16
    const float* __restrict__ lp,    // [KSPLIT][BH][T]
    const float* __restrict__ x,     // [B][C][T] fp32 residual
    float* __restrict__ out)         // [B][C][T] fp32
{
    const int b  = blockIdx.z;
    const int t0 = blockIdx.x * 64;
    const int o0 = blockIdx.y * 64;

    __shared__ short sm[8192];       // A 8x512 + B 8x512 shorts (16 KiB)
    short* Ab = sm;
    short* Bb = sm + 4096;

    const int tid = threadIdx.x, lane = tid & 63, wave = tid >> 6;
    const int col = lane & 15, quad = lane >> 4;

    const int trow = t0 + 16*wave + col;
    float rl4[NH];
    #pragma unroll
    for (int hh = 0; hh < NH; hh++) {
        float ls = 0.f;
        #pragma unroll
        for (int ks = 0; ks < KSPLIT; ks++)
            ls += lp[((size_t)(ks*BH) + b*NH + hh) * T + trow];
        rl4[hh] = 1.0f / ls;
    }

    f32x4 acc[4];
    #pragma unroll
    for (int g = 0; g < 4; g++) { acc[g][0]=0.f; acc[g][1]=0.f; acc[g][2]=0.f; acc[g][3]=0.f; }

    for (int k0 = 0; k0 < C; k0 += 64) {
        __syncthreads();
        #pragma unroll
        for (int hh = 0; hh < 2; hh++) {
            gll16(wp + (size_t)(o0 + 16*wave + col) * C + k0 + hh*32 + quad*8,
                  Ab + (hh*4 + wave) * 512);
            const int chg = k0 + hh*32 + quad*8;       // global channel
            const int hd = chg >> 6, chin = chg & 63;  // hd is wave-uniform
            const short* ob = opart + (((size_t)(b*NH + hd)) * T + trow) * 64 + chin;
            float a8[8] = {0.f,0.f,0.f,0.f,0.f,0.f,0.f,0.f};
            #pragma unroll
            for (int ks = 0; ks < KSPLIT; ks++) {
                bfv8 v = *(const bfv8*)(ob + (size_t)ks * BH * T * 64);
                #pragma unroll
                for (int u = 0; u < 8; u++) a8[u] += bf2f(v[u]);
            }
            const float rl = rl4[hd];
            bfv8 pk;
            #pragma unroll
            for (int u = 0; u < 8; u++) pk[u] = f2bf(a8[u] * rl);
            *(bfv8*)(Bb + (hh*4 + wave) * 512 + lane*8) = pk;
        }
        __syncthreads();
        #pragma unroll
        for (int hh = 0; hh < 2; hh++) {
            bfv8 af = *(const bfv8*)(Ab + (hh*4 + wave) * 512 + lane*8);
            #pragma unroll
            for (int g = 0; g < 4; g++) {
                bfv8 bf = *(const bfv8*)(Bb + (hh*4 + g) * 512 + lane*8);
                acc[g] = __builtin_amdgcn_mfma_f32_16x16x32_bf16(af, bf, acc[g], 0, 0, 0);
            }
        }
    }

    const int olocal = 16*wave + quad*4;
    #pragma unroll
    for (int r = 0; r < 4; r++) {
        const int o = o0 + olocal + r;
        const float bias = bp[o];
        const size_t rowoff = ((size_t)b * C + o) * T;
        #pragma unroll
        for (int g = 0; g < 4; g++) {
            const size_t idx = rowoff + t0 + 16*g + col;
            out[idx] = acc[g][r] + bias + x[idx];
        }
    }
}

// ---------------------------------------------------------------------------
extern "C" void kernel_launch(void* const* d_in, const int* in_sizes, int n_in,
                              void* d_out, int out_size, void* d_ws, size_t ws_size,
                              hipStream_t stream) {
    (void)in_sizes; (void)n_in; (void)out_size; (void)ws_size;
    const float* x        = (const float*)d_in[0];
    const float* gn_scale = (const float*)d_in[1];
    const float* gn_bias  = (const float*)d_in[2];
    const float* w_qkv    = (const float*)d_in[3];
    const float* b_qkv    = (const float*)d_in[4];
    const float* w_proj   = (const float*)d_in[5];
    const float* b_proj   = (const float*)d_in[6];
    float* out = (float*)d_out;

    short* ws    = (short*)d_ws;
    short* qb    = ws;                                  // [BH][T][64]
    short* kb    = qb  + (size_t)BH * T * 64;
    short* vb    = kb  + (size_t)BH * T * 64;
    short* xnT   = vb  + (size_t)BH * T * 64;           // [B][T][C]
    short* wqb   = xnT + (size_t)BATCH * T * C;
    short* wpb   = wqb + 768 * 256;
    short* opart = wpb + 256 * 256;                     // [4][BH][T][64] bf16
    float* lp    = (float*)(opart + (size_t)KSPLIT * BH * T * 64);  // [4][BH][T]
    float* gnp   = lp + (size_t)KSPLIT * BH * T;        // [64][4][2]

    prep_w<<<dim3(256), 256, 0, stream>>>(w_qkv, w_proj, wqb, wpb);
    gn_stats<<<dim3(BATCH * G, 4), 256, 0, stream>>>(x, gnp);
    gn_norm<<<dim3(BATCH * G, 4), 256, 0, stream>>>(x, gn_scale, gn_bias, gnp, xnT);
    gemm_qkv<<<dim3(T/64, 12, BATCH), 256, 0, stream>>>(wqb, b_qkv, xnT, qb, kb, vb);
    attn_kernel<<<dim3(T/256, BH, KSPLIT), 512, 0, stream>>>(qb, kb, vb, opart, lp);
    gemm_proj<<<dim3(T/64, 4, BATCH), 256, 0, stream>>>(wpb, b_proj, opart, lp, x, out);
}